// Round 12
// baseline (192.512 us; speedup 1.0000x reference)
//
#include <hip/hip_runtime.h>

// DeformableTemporalAttention — MI355X (gfx950)
// B=4, N=4096 (64x64), T=3, D=256, H=8, P=9, dh=32
//
// Pipeline (3 dispatches):
//  1. mgemm01 : A staged straight from x (t-sum + fp16 hi/lo split in staging),
//               B = weights transposed+converted in-LDS during staging.
//               yy<4: valsum(fp16) = (sum_t x) @ W_v + 3*b_v   (A hi/lo x B, 2-pass)
//               yy>=4: proj(f32)   = x[:,:,1,:] @ [W_off|W_attn] + bias (3-pass)
//               XCD-grouped grid: all 8 blocks of an m-tile on one XCD.
//  2. sample8 : 8 px/block, 2 px/wave, f16x8 gathers -> inter fp16 hi/lo
//  3. mgemm2  : out = inter @ W_o + b_o (W_o transposed in-LDS, 2-pass)

#define NH_ 8
#define DH_ 32
#define MM_ 16384   // B*N

typedef __attribute__((ext_vector_type(8))) _Float16 f16x8;
typedef __attribute__((ext_vector_type(4))) _Float16 f16x4;
typedef __attribute__((ext_vector_type(4))) float f32x4;

struct HL { _Float16 h, l; };
static __device__ __forceinline__ HL fsplit(float f) {
  HL r;
  r.h = (_Float16)f;
  r.l = (_Float16)(f - (float)r.h);
  return r;
}

// ---------------- fused GEMM: valsum (yy<4) + proj (yy>=4) -----------------
// BM=BN=BK=64; 4 waves (2x2), wave tile 32x32. Reg-prefetch pipeline.
// bid: c=bid&7 (XCD), local=bid>>3; yy=local&7; mt=(local>>3)*8+c.
__global__ __launch_bounds__(256, 3) void mgemm01(
    const float* __restrict__ x,
    const float* __restrict__ W_off, const float* __restrict__ W_attn,
    const float* __restrict__ W_v,
    const float* __restrict__ b_off, const float* __restrict__ b_attn,
    const float* __restrict__ b_v,
    _Float16* __restrict__ valsum, float* __restrict__ proj) {
  __shared__ _Float16 Ah[64 * 64], Al[64 * 64], Bh[64 * 64], Bl[64 * 64];
  const int bid = blockIdx.x;
  const int xcd = bid & 7, local = bid >> 3;
  const int yy = local & 7;
  const int m0 = ((local >> 3) * 8 + xcd) * 64;
  const int mode1 = yy >= 4;
  const int n0 = (yy & 3) * 64;
  const int tid = threadIdx.x, wid = tid >> 6, lane = tid & 63;
  const int am = (wid >> 1) * 32, bn = (wid & 1) * 32;
  const int fr = lane & 15, kg = lane >> 4;

  // A staging: thread covers rows r0s and r0s+32, 8 k-elems each
  const int r0s = tid >> 3, c0s = tid & 7;
  const int r1s = r0s + 32;
  const int d0s = r0s * 64 + ((c0s ^ (r0s & 7)) * 8);
  const int d1s = r1s * 64 + ((c0s ^ (r1s & 7)) * 8);
  // B staging (transpose): thread covers n-rows bnn..+3, k bkk..+3
  const int bnn = (tid >> 4) * 4;
  const int bkk = (tid & 15) * 4;

  f32x4 acc[2][2];
#pragma unroll
  for (int i = 0; i < 2; ++i)
#pragma unroll
    for (int j = 0; j < 2; ++j) acc[i][j] = (f32x4)(0.f);

  float4 pA[2][6];     // mode0: 6 float4/row (3 t-slices); mode1: 2 used
  float pBv[16];       // B tile values

#define LOADT(k0)                                                            \
  {                                                                          \
    if (mode1) {                                                             \
      const float* s0 = x + (size_t)(m0 + r0s) * 768 + 256 + (k0) + c0s * 8; \
      const float* s1 = x + (size_t)(m0 + r1s) * 768 + 256 + (k0) + c0s * 8; \
      pA[0][0] = *(const float4*)s0; pA[0][1] = *(const float4*)(s0 + 4);    \
      pA[1][0] = *(const float4*)s1; pA[1][1] = *(const float4*)(s1 + 4);    \
      _Pragma("unroll")                                                      \
      for (int j = 0; j < 4; ++j) {                                          \
        const int kglob = (k0) + bkk + j;                                    \
        _Pragma("unroll")                                                    \
        for (int i = 0; i < 4; ++i) {                                        \
          const int gn = n0 + bnn + i;                                       \
          float v = 0.f;                                                     \
          if (gn < 144) v = W_off[(size_t)kglob * 144 + gn];                 \
          else if (gn < 216) v = W_attn[(size_t)kglob * 72 + (gn - 144)];    \
          pBv[j * 4 + i] = v;                                                \
        }                                                                    \
      }                                                                      \
    } else {                                                                 \
      const float* s0 = x + (size_t)(m0 + r0s) * 768 + (k0) + c0s * 8;       \
      const float* s1 = x + (size_t)(m0 + r1s) * 768 + (k0) + c0s * 8;       \
      pA[0][0] = *(const float4*)s0;         pA[0][1] = *(const float4*)(s0 + 4);   \
      pA[0][2] = *(const float4*)(s0 + 256); pA[0][3] = *(const float4*)(s0 + 260); \
      pA[0][4] = *(const float4*)(s0 + 512); pA[0][5] = *(const float4*)(s0 + 516); \
      pA[1][0] = *(const float4*)s1;         pA[1][1] = *(const float4*)(s1 + 4);   \
      pA[1][2] = *(const float4*)(s1 + 256); pA[1][3] = *(const float4*)(s1 + 260); \
      pA[1][4] = *(const float4*)(s1 + 512); pA[1][5] = *(const float4*)(s1 + 516); \
      _Pragma("unroll")                                                      \
      for (int j = 0; j < 4; ++j)                                            \
        *(float4*)&pBv[j * 4] =                                              \
            *(const float4*)(W_v + (size_t)((k0) + bkk + j) * 256 + n0 + bnn);\
    }                                                                        \
  }

#define WRITET()                                                             \
  {                                                                          \
    _Pragma("unroll")                                                        \
    for (int hh = 0; hh < 2; ++hh) {                                         \
      float s[8];                                                            \
      if (mode1) {                                                           \
        _Pragma("unroll")                                                    \
        for (int q = 0; q < 4; ++q) { s[q] = pA[hh][0][q]; s[4 + q] = pA[hh][1][q]; } \
      } else {                                                               \
        _Pragma("unroll")                                                    \
        for (int q = 0; q < 4; ++q) {                                        \
          s[q] = pA[hh][0][q] + pA[hh][2][q] + pA[hh][4][q];                 \
          s[4 + q] = pA[hh][1][q] + pA[hh][3][q] + pA[hh][5][q];             \
        }                                                                    \
      }                                                                      \
      f16x8 hv, lv;                                                          \
      _Pragma("unroll")                                                      \
      for (int q = 0; q < 8; ++q) { HL r = fsplit(s[q]); hv[q] = r.h; lv[q] = r.l; } \
      const int dd = hh ? d1s : d0s;                                         \
      *(f16x8*)(Ah + dd) = hv; *(f16x8*)(Al + dd) = lv;                      \
    }                                                                        \
    _Pragma("unroll")                                                        \
    for (int j = 0; j < 4; ++j) {                                            \
      _Pragma("unroll")                                                      \
      for (int i = 0; i < 4; ++i) {                                          \
        const int row = bnn + i, kk2 = bkk + j;                              \
        const int el = row * 64 + (((kk2 >> 3) ^ (row & 7)) * 8) + (kk2 & 7);\
        if (mode1) {                                                         \
          HL r = fsplit(pBv[j * 4 + i]);                                     \
          Bh[el] = r.h; Bl[el] = r.l;                                        \
        } else {                                                             \
          Bh[el] = (_Float16)pBv[j * 4 + i];                                 \
        }                                                                    \
      }                                                                      \
    }                                                                        \
  }

#define COMPUTET()                                                           \
  _Pragma("unroll")                                                          \
  for (int ks = 0; ks < 2; ++ks) {                                           \
    const int kc = ks * 4 + kg;                                              \
    f16x8 ah[2], al[2];                                                      \
    _Pragma("unroll")                                                        \
    for (int mi = 0; mi < 2; ++mi) {                                         \
      int m = am + mi * 16 + fr;                                             \
      int o = m * 64 + ((kc ^ (m & 7)) * 8);                                 \
      ah[mi] = *(const f16x8*)(Ah + o);                                      \
      al[mi] = *(const f16x8*)(Al + o);                                      \
    }                                                                        \
    _Pragma("unroll")                                                        \
    for (int ni = 0; ni < 2; ++ni) {                                         \
      int nn = bn + ni * 16 + fr;                                            \
      int o = nn * 64 + ((kc ^ (nn & 7)) * 8);                               \
      f16x8 bh = *(const f16x8*)(Bh + o);                                    \
      _Pragma("unroll")                                                      \
      for (int mi = 0; mi < 2; ++mi) {                                       \
        acc[mi][ni] = __builtin_amdgcn_mfma_f32_16x16x32_f16(ah[mi], bh, acc[mi][ni], 0, 0, 0);\
        acc[mi][ni] = __builtin_amdgcn_mfma_f32_16x16x32_f16(al[mi], bh, acc[mi][ni], 0, 0, 0);\
      }                                                                      \
      if (mode1) {                                                           \
        f16x8 bl = *(const f16x8*)(Bl + o);                                  \
        _Pragma("unroll")                                                    \
        for (int mi = 0; mi < 2; ++mi)                                       \
          acc[mi][ni] = __builtin_amdgcn_mfma_f32_16x16x32_f16(ah[mi], bl, acc[mi][ni], 0, 0, 0);\
      }                                                                      \
    }                                                                        \
  }

  LOADT(0);
  WRITET();
  __syncthreads();
#pragma unroll
  for (int t = 0; t < 4; ++t) {
    if (t < 3) LOADT((t + 1) * 64);
    COMPUTET();
    __syncthreads();
    if (t < 3) { WRITET(); __syncthreads(); }
  }

  const int ro = kg * 4;
#pragma unroll
  for (int mi = 0; mi < 2; ++mi)
#pragma unroll
    for (int ni = 0; ni < 2; ++ni) {
      int col = n0 + bn + ni * 16 + fr;
      if (mode1 && col >= 216) continue;
      int rowb = m0 + am + mi * 16 + ro;
      float bv = mode1 ? (col < 144 ? b_off[col] : b_attn[col - 144])
                       : b_v[col] * 3.f;
#pragma unroll
      for (int r = 0; r < 4; ++r) {
        int grow = rowb + r;
        float v = acc[mi][ni][r] + bv;
        if (mode1) {
          proj[(size_t)grow * 216 + col] = v;
        } else {
          int b = grow >> 12, nn2 = grow & 4095;
          int h = col >> 5, d = col & 31;
          valsum[(((size_t)(b * NH_ + h) << 12) + nn2) * DH_ + d] = (_Float16)v;
        }
      }
    }
#undef LOADT
#undef WRITET
#undef COMPUTET
}

// ---------------- O-GEMM: out = inter(fp16 hi/lo) @ W_o + b_o (2-pass) -----
__global__ __launch_bounds__(256, 4) void mgemm2(
    const _Float16* __restrict__ Ahi, const _Float16* __restrict__ Alo,
    const float* __restrict__ W_o,
    const float* __restrict__ b_o, float* __restrict__ Cout) {
  __shared__ _Float16 Ah[64 * 64], Al[64 * 64], Bh[64 * 64];
  const int bid = blockIdx.x;
  const int flat = (bid & 7) * 128 + (bid >> 3);   // XCD-chunked (1024 % 8 == 0)
  const int m0 = (flat >> 2) * 64;
  const int n0 = (flat & 3) * 64;
  const int tid = threadIdx.x, wid = tid >> 6, lane = tid & 63;
  const int am = (wid >> 1) * 32, bn = (wid & 1) * 32;
  const int fr = lane & 15, kg = lane >> 4;

  const int r0s = tid >> 3, c0s = tid & 7;
  const int r1s = r0s + 32;
  const int d0s = r0s * 64 + ((c0s ^ (r0s & 7)) * 8);
  const int d1s = r1s * 64 + ((c0s ^ (r1s & 7)) * 8);
  const int bnn = (tid >> 4) * 4;
  const int bkk = (tid & 15) * 4;

  f32x4 acc[2][2];
#pragma unroll
  for (int i = 0; i < 2; ++i)
#pragma unroll
    for (int j = 0; j < 2; ++j) acc[i][j] = (f32x4)(0.f);

  f16x8 pah[2], pal[2];
  float pBv[16];

#define LOADT2(k0)                                                           \
  {                                                                          \
    size_t a0 = (size_t)(m0 + r0s) * 256 + (k0) + c0s * 8;                   \
    size_t a1 = (size_t)(m0 + r1s) * 256 + (k0) + c0s * 8;                   \
    pah[0] = *(const f16x8*)(Ahi + a0); pal[0] = *(const f16x8*)(Alo + a0);  \
    pah[1] = *(const f16x8*)(Ahi + a1); pal[1] = *(const f16x8*)(Alo + a1);  \
    _Pragma("unroll")                                                        \
    for (int j = 0; j < 4; ++j)                                              \
      *(float4*)&pBv[j * 4] =                                                \
          *(const float4*)(W_o + (size_t)((k0) + bkk + j) * 256 + n0 + bnn); \
  }

#define WRITET2()                                                            \
  {                                                                          \
    *(f16x8*)(Ah + d0s) = pah[0]; *(f16x8*)(Al + d0s) = pal[0];              \
    *(f16x8*)(Ah + d1s) = pah[1]; *(f16x8*)(Al + d1s) = pal[1];              \
    _Pragma("unroll")                                                        \
    for (int j = 0; j < 4; ++j)                                              \
      _Pragma("unroll")                                                      \
      for (int i = 0; i < 4; ++i) {                                          \
        const int row = bnn + i, kk2 = bkk + j;                              \
        const int el = row * 64 + (((kk2 >> 3) ^ (row & 7)) * 8) + (kk2 & 7);\
        Bh[el] = (_Float16)pBv[j * 4 + i];                                   \
      }                                                                      \
  }

#define COMPUTET2()                                                          \
  _Pragma("unroll")                                                          \
  for (int ks = 0; ks < 2; ++ks) {                                           \
    const int kc = ks * 4 + kg;                                              \
    f16x8 ah[2], al[2], bh[2];                                               \
    _Pragma("unroll")                                                        \
    for (int mi = 0; mi < 2; ++mi) {                                         \
      int m = am + mi * 16 + fr;                                             \
      int o = m * 64 + ((kc ^ (m & 7)) * 8);                                 \
      ah[mi] = *(const f16x8*)(Ah + o);                                      \
      al[mi] = *(const f16x8*)(Al + o);                                      \
    }                                                                        \
    _Pragma("unroll")                                                        \
    for (int ni = 0; ni < 2; ++ni) {                                         \
      int nn = bn + ni * 16 + fr;                                            \
      int o = nn * 64 + ((kc ^ (nn & 7)) * 8);                               \
      bh[ni] = *(const f16x8*)(Bh + o);                                      \
    }                                                                        \
    _Pragma("unroll")                                                        \
    for (int mi = 0; mi < 2; ++mi)                                           \
      _Pragma("unroll")                                                      \
      for (int ni = 0; ni < 2; ++ni) {                                       \
        acc[mi][ni] = __builtin_amdgcn_mfma_f32_16x16x32_f16(ah[mi], bh[ni], acc[mi][ni], 0, 0, 0);\
        acc[mi][ni] = __builtin_amdgcn_mfma_f32_16x16x32_f16(al[mi], bh[ni], acc[mi][ni], 0, 0, 0);\
      }                                                                      \
  }

  LOADT2(0);
  WRITET2();
  __syncthreads();
#pragma unroll
  for (int t = 0; t < 4; ++t) {
    if (t < 3) LOADT2((t + 1) * 64);
    COMPUTET2();
    __syncthreads();
    if (t < 3) { WRITET2(); __syncthreads(); }
  }

  const int ro = kg * 4;
#pragma unroll
  for (int mi = 0; mi < 2; ++mi)
#pragma unroll
    for (int ni = 0; ni < 2; ++ni) {
      int col = n0 + bn + ni * 16 + fr;
      int rowb = m0 + am + mi * 16 + ro;
      float bv = b_o[col];
#pragma unroll
      for (int r = 0; r < 4; ++r)
        Cout[(size_t)(rowb + r) * 256 + col] = acc[mi][ni][r] + bv;
    }
#undef LOADT2
#undef WRITET2
#undef COMPUTET2
}

// ---------------- sampler: 8 px / block, 2 px / wave, f16x8 gathers --------
struct IW { int idx; float w; };

__global__ __launch_bounds__(256) void sample8(const _Float16* __restrict__ valsum,
                                               const float* __restrict__ proj,
                                               _Float16* __restrict__ ihi,
                                               _Float16* __restrict__ ilo) {
  const int bid = blockIdx.x;                 // 2048 blocks
  const int base = ((bid & 7) << 11) + ((bid >> 3) << 3);   // XCD-chunked
  const int tid = threadIdx.x;

  __shared__ IW cwi[8][72][4];
  __shared__ float sap[8][72];

  // softmax: 64 (px, h) entries
  if (tid < 64) {
    const int ps = tid >> 3, h = tid & 7;
    const int row_s = base + ps;
    const float* pa = proj + (size_t)row_s * 216 + 144 + h * 9;
    float lg[9], mx = -1e30f;
#pragma unroll
    for (int p = 0; p < 9; ++p) { lg[p] = pa[p]; mx = fmaxf(mx, lg[p]); }
    float s = 0.f;
#pragma unroll
    for (int p = 0; p < 9; ++p) { lg[p] = __expf(lg[p] - mx); s += lg[p]; }
    float inv = 1.f / s;
#pragma unroll
    for (int p = 0; p < 9; ++p) sap[ps][h * 9 + p] = lg[p] * inv;
  }
  __syncthreads();
  // corners: 576 (px, point) entries, attn folded in
  for (int e = tid; e < 576; e += 256) {
    const int ps = e / 72;
    const int pt = e - ps * 72;
    const int row_s = base + ps;
    const int n = row_s & 4095;
    const float* pr = proj + (size_t)row_s * 216;
    float ox = pr[pt * 2], oy = pr[pt * 2 + 1];
    float gx = (float)(n & 63) + ox * 31.5f;
    float gy = (float)(n >> 6) + oy * 31.5f;
    float fx0 = floorf(gx), fy0 = floorf(gy);
    float wx1 = gx - fx0, wy1 = gy - fy0;
    float wx0 = 1.f - wx1, wy0 = 1.f - wy1;
    int x0 = (int)fx0, y0 = (int)fy0, x1 = x0 + 1, y1 = y0 + 1;
    bool vx0 = (x0 >= 0) & (x0 < 64), vx1 = (x1 >= 0) & (x1 < 64);
    bool vy0 = (y0 >= 0) & (y0 < 64), vy1 = (y1 >= 0) & (y1 < 64);
    int x0c = min(max(x0, 0), 63), x1c = min(max(x1, 0), 63);
    int y0c = min(max(y0, 0), 63), y1c = min(max(y1, 0), 63);
    const float a = sap[ps][pt];
    cwi[ps][pt][0] = IW{(y0c * 64 + x0c) * DH_, (vx0 & vy0) ? wx0 * wy0 * a : 0.f};
    cwi[ps][pt][1] = IW{(y0c * 64 + x1c) * DH_, (vx1 & vy0) ? wx1 * wy0 * a : 0.f};
    cwi[ps][pt][2] = IW{(y1c * 64 + x0c) * DH_, (vx0 & vy1) ? wx0 * wy1 * a : 0.f};
    cwi[ps][pt][3] = IW{(y1c * 64 + x1c) * DH_, (vx1 & vy1) ? wx1 * wy1 * a : 0.f};
  }
  __syncthreads();

  const int px = tid >> 5, lane32 = tid & 31;
  const int row = base + px;
  const int b = row >> 12;
  const int h = lane32 >> 2, d8 = (lane32 & 3) * 8;
  const _Float16* vb = valsum + (((size_t)(b * NH_ + h)) << 12) * DH_ + d8;
  float acc[8];
#pragma unroll
  for (int k = 0; k < 8; ++k) acc[k] = 0.f;

#pragma unroll
  for (int pb = 0; pb < 9; pb += 3) {
    f16x8 v[12]; float w[12];
#pragma unroll
    for (int q = 0; q < 3; ++q) {
      const int hp = h * 9 + pb + q;
#pragma unroll
      for (int c = 0; c < 4; ++c) {
        IW e = cwi[px][hp][c];
        v[q * 4 + c] = *(const f16x8*)(vb + e.idx);
        w[q * 4 + c] = e.w;
      }
    }
#pragma unroll
    for (int j = 0; j < 12; ++j)
#pragma unroll
      for (int k = 0; k < 8; ++k) acc[k] += w[j] * (float)v[j][k];
  }

  f16x8 hv, lv;
#pragma unroll
  for (int k = 0; k < 8; ++k) {
    HL r = fsplit(acc[k]);
    hv[k] = r.h; lv[k] = r.l;
  }
  const size_t o = (size_t)row * 256 + h * DH_ + d8;
  *(f16x8*)(ihi + o) = hv;
  *(f16x8*)(ilo + o) = lv;
}

extern "C" void kernel_launch(void* const* d_in, const int* in_sizes, int n_in,
                              void* d_out, int out_size, void* d_ws, size_t ws_size,
                              hipStream_t stream) {
  const float* x      = (const float*)d_in[0];
  const float* W_off  = (const float*)d_in[1];
  const float* b_off  = (const float*)d_in[2];
  const float* W_attn = (const float*)d_in[3];
  const float* b_attn = (const float*)d_in[4];
  const float* W_v    = (const float*)d_in[5];
  const float* b_v    = (const float*)d_in[6];
  const float* W_o    = (const float*)d_in[7];
  const float* b_o    = (const float*)d_in[8];
  float* out = (float*)d_out;

  // ---- workspace layout
  _Float16* valsum = (_Float16*)d_ws;                    // 16384*256 fp16 (8 MB)
  float* proj      = (float*)(valsum + (size_t)MM_ * 256); // 16384*216 f32
  _Float16* ihi    = (_Float16*)(proj + (size_t)MM_ * 216); // 16384*256 fp16
  _Float16* ilo    = ihi + (size_t)MM_ * 256;

  mgemm01<<<dim3(2048), dim3(256), 0, stream>>>(x, W_off, W_attn, W_v,
                                                b_off, b_attn, b_v, valsum, proj);
  sample8<<<dim3(2048), dim3(256), 0, stream>>>(valsum, proj, ihi, ilo);
  mgemm2<<<dim3(1024), dim3(256), 0, stream>>>(ihi, ilo, W_o, b_o, out);
}